// Round 5
// baseline (288.895 us; speedup 1.0000x reference)
//
#include <hip/hip_runtime.h>
#include <hip/hip_bf16.h>

// SCM_39676907888322: sigmoid-gated cross attention. fp32 I/O, bf16 MFMA compute.
// R9: barrier-free attn. R6/R8 were serialized by two block barriers per m-tile
// (MfmaUtil ~17-19% = exact serial-sum of phases). K/V/Q per (b,dir) = 3.5 MB,
// XCD-pinned -> L2-resident, so LDS staging is pure overhead (m169 lesson).
// New attn: 1152 blocks (8b x 2dir x 72nt) x 4 waves; wave = m-quarter, sweeps
// 18 tiles of 32 m reading K/V fragments DIRECTLY from L2 (16B contiguous).
// No LDS, no barriers in main loop; 4-way LDS reduction tree only at the end.
// Vt re-laid out as [mt][c][32] (qkv epilogue change) so PV A-frags are
// contiguous 16B with full 64B-line use.

typedef __bf16 bf16;
typedef __bf16 bf16x8 __attribute__((ext_vector_type(8)));
typedef __bf16 bf16x4 __attribute__((ext_vector_type(4)));
typedef float f32x4 __attribute__((ext_vector_type(4)));
typedef float f32x16 __attribute__((ext_vector_type(16)));
typedef unsigned int u32x4 __attribute__((ext_vector_type(4)));

#define NB 8
#define NC 256
#define NCI 128
#define NHW 2304
#define NT32 72    // 2304 / 32  (qkv n-tiles)

__global__ __launch_bounds__(256) void wconv_kernel(
    const float* __restrict__ w0, const float* __restrict__ w1,
    const float* __restrict__ w2, const float* __restrict__ w3,
    const float* __restrict__ w4, const float* __restrict__ w5,
    bf16* __restrict__ dst)
{
    int idx = (blockIdx.x * 256 + threadIdx.x) * 8;   // 6*32768 total
    int m = idx >> 15;                                 // matrix id (block-uniform)
    int off = idx & 32767;
    const float* w = (m == 0) ? w0 : (m == 1) ? w1 : (m == 2) ? w2
                   : (m == 3) ? w3 : (m == 4) ? w4 : w5;
    f32x4 a0 = *(const f32x4*)(w + off);
    f32x4 a1 = *(const f32x4*)(w + off + 4);
    bf16x8 o;
    #pragma unroll
    for (int j = 0; j < 4; ++j) { o[j] = (bf16)a0[j]; o[4 + j] = (bf16)a1[j]; }
    *(bf16x8*)(dst + idx) = o;
}

__global__ __launch_bounds__(256) void qkv_kernel(
    const float* __restrict__ x1, const float* __restrict__ x2,
    const bf16* __restrict__ wb,
    const float* __restrict__ bv1, const float* __restrict__ bk1, const float* __restrict__ bq1,
    const float* __restrict__ bv2, const float* __restrict__ bk2, const float* __restrict__ bq2,
    bf16* __restrict__ Qt, bf16* __restrict__ Kt, bf16* __restrict__ Vt,
    float* __restrict__ out)
{
    // Xt[n][c] bf16, 32 rows, padded stride 264
    __shared__ __align__(16) bf16 Xt[32 * 264];

    int gid = blockIdx.x;
    int nt = gid % NT32;
    int s = (gid / NT32) & 1;
    int b = gid / (2 * NT32);
    int n0 = nt * 32;

    const float* x = s ? x2 : x1;
    // wb layout: [v1,k1,q1,v2,k2,q2] each 128*256
    const bf16* wv = wb + (size_t)(s * 3 + 0) * (NCI * NC);
    const bf16* wk = wb + (size_t)(s * 3 + 1) * (NCI * NC);
    const bf16* wq = wb + (size_t)(s * 3 + 2) * (NCI * NC);
    const float* bv = s ? bv2 : bv1;
    const float* bk = s ? bk2 : bk1;
    const float* bq = s ? bq2 : bq1;
    float* outy = out + (size_t)s * (NB * 384 * NHW);

    int tid = threadIdx.x;
    // Stage X tile (256 c x 32 n) into LDS transposed (bf16); fp32 concat passthrough.
    {
        int n_off = (tid & 3) * 8;       // 0,8,16,24
        int c0l = tid >> 2;              // 0..63
        #pragma unroll
        for (int i = 0; i < 4; ++i) {
            int c = c0l + i * 64;
            const float* src = x + ((size_t)(b * NC + c) * NHW + n0 + n_off);
            f32x4 a0 = *(const f32x4*)src;
            f32x4 a1 = *(const f32x4*)(src + 4);
            float* dsty = outy + ((size_t)(b * 384 + c) * NHW + n0 + n_off);
            *(f32x4*)dsty = a0;
            *(f32x4*)(dsty + 4) = a1;
            #pragma unroll
            for (int j = 0; j < 4; ++j) {
                Xt[(n_off + j) * 264 + c] = (bf16)a0[j];
                Xt[(n_off + 4 + j) * 264 + c] = (bf16)a1[j];
            }
        }
    }
    __syncthreads();

    int lane = tid & 63;
    int wid = tid >> 6;                  // wave 0..3 -> ci strip of 32
    int row = lane & 15, quad = lane >> 4;
    int ci_base = wid * 32;

    f32x4 acc[3][2][2];                  // [q,k,v][mi][j]
    #pragma unroll
    for (int t = 0; t < 3; ++t)
        #pragma unroll
        for (int mi = 0; mi < 2; ++mi)
            #pragma unroll
            for (int j = 0; j < 2; ++j)
                acc[t][mi][j] = (f32x4){0.f, 0.f, 0.f, 0.f};

    const bf16* wptr[3] = {wq, wk, wv};
    #pragma unroll
    for (int ks = 0; ks < 8; ++ks) {
        int c0 = ks * 32 + quad * 8;
        bf16x8 bfrag[2];
        #pragma unroll
        for (int j = 0; j < 2; ++j)
            bfrag[j] = *(const bf16x8*)&Xt[(j * 16 + row) * 264 + c0];
        #pragma unroll
        for (int t = 0; t < 3; ++t) {
            #pragma unroll
            for (int mi = 0; mi < 2; ++mi) {
                bf16x8 afrag = *(const bf16x8*)&wptr[t][(size_t)(ci_base + mi * 16 + row) * NC + c0];
                #pragma unroll
                for (int j = 0; j < 2; ++j)
                    acc[t][mi][j] = __builtin_amdgcn_mfma_f32_16x16x32_bf16(
                        afrag, bfrag[j], acc[t][mi][j], 0, 0, 0);
            }
        }
    }

    // Epilogue: +bias (fp32), write Qt/Kt (n,128) bf16 8B stores.
    // V goes to the TILED layout Vt[(s,b)][mt(72)][c(128)][mm(32)] so attn's
    // PV A-frags are 16B-contiguous (this block covers exactly tile mt = nt).
    size_t qkbase = ((size_t)s * NB + b) * NHW * NCI;
    size_t vbase  = ((size_t)s * NB + b) * NCI * NHW;
    #pragma unroll
    for (int mi = 0; mi < 2; ++mi) {
        int ci0 = ci_base + mi * 16 + quad * 4;
        f32x4 bq4 = *(const f32x4*)&bq[ci0];
        f32x4 bk4 = *(const f32x4*)&bk[ci0];
        f32x4 bv4 = *(const f32x4*)&bv[ci0];
        #pragma unroll
        for (int j = 0; j < 2; ++j) {
            int n = n0 + j * 16 + row;   // D col = lane&15
            bf16x4 pk;
            #pragma unroll
            for (int r = 0; r < 4; ++r) pk[r] = (bf16)(acc[0][mi][j][r] + bq4[r]);
            *(bf16x4*)&Qt[qkbase + (size_t)n * NCI + ci0] = pk;
            #pragma unroll
            for (int r = 0; r < 4; ++r) pk[r] = (bf16)(acc[1][mi][j][r] + bk4[r]);
            *(bf16x4*)&Kt[qkbase + (size_t)n * NCI + ci0] = pk;
            #pragma unroll
            for (int r = 0; r < 4; ++r)
                Vt[vbase + (size_t)(nt * 128 + ci0 + r) * 32 + (j * 16 + row)] =
                    (bf16)(acc[2][mi][j][r] + bv4[r]);
        }
    }
}

__global__ __launch_bounds__(256, 3) void attn_kernel(
    const bf16* __restrict__ Qt, const bf16* __restrict__ Kt, const bf16* __restrict__ Vt,
    float* __restrict__ out)
{
    __shared__ __align__(16) float RED[8192];   // 32 KB, epilogue reduction only

    int gid = blockIdx.x;                // 1152 = 8 b x 2 dir x 72 nt
    int b = gid & 7;                     // XCD pin: all blocks of batch b -> XCD b
    int dir = (gid >> 3) & 1;
    int nt = gid >> 4;                   // 0..71

    int tid = threadIdx.x;
    int lane = tid & 63;
    int mq = tid >> 6;                   // wave -> m-quarter (576 m rows, 18 tiles)
    int col = lane & 31, hi = lane >> 5;

    int sq = dir, skv = dir ^ 1;
    const bf16* q = Qt + ((size_t)sq  * NB + b) * (NHW * NCI);
    const bf16* k = Kt + ((size_t)skv * NB + b) * (NHW * NCI);
    const bf16* v = Vt + ((size_t)skv * NB + b) * (NCI * NHW);   // tiled [mt][c][32]
    float* outy = out + (size_t)dir * (NB * 384 * NHW) + ((size_t)b * 384 + 256) * NHW;

    int nw = nt * 32;                    // block's 32 Q rows (shared by all 4 waves)

    bf16x8 qf[8];                        // Q B-frags, resident
    #pragma unroll
    for (int j = 0; j < 8; ++j)
        qf[j] = *(const bf16x8*)&q[(size_t)(nw + col) * NCI + j * 16 + hi * 8];

    f32x16 o0, o1, o2, o3;               // O^T partial acc (this wave's m-quarter)
    #pragma unroll
    for (int j = 0; j < 16; ++j) { o0[j] = 0.f; o1[j] = 0.f; o2[j] = 0.f; o3[j] = 0.f; }

    for (int i = 0; i < 18; ++i) {
        int m0 = mq * 576 + i * 32;
        const bf16* kp = k + (size_t)(m0 + col) * NCI + hi * 8;

        // S^T = K * Q^T : 32 m x 32 n, K-frags straight from L2 (16B contiguous)
        f32x16 s;
        #pragma unroll
        for (int j = 0; j < 16; ++j) s[j] = 0.f;
        __builtin_amdgcn_s_setprio(1);
        #pragma unroll
        for (int j = 0; j < 8; ++j) {
            bf16x8 kf = *(const bf16x8*)(kp + j * 16);
            s = __builtin_amdgcn_mfma_f32_32x32x16_bf16(kf, qf[j], s, 0, 0, 0);
        }
        __builtin_amdgcn_s_setprio(0);

        // sigmoid in place (S^T reg r = S^T[m=(r&3)+8*(r>>2)+4*hi][n=col])
        #pragma unroll
        for (int r = 0; r < 16; ++r) {
            float e = __expf(-s[r]);
            s[r] = __builtin_amdgcn_rcpf(1.0f + e);
        }
        // P^T bf16 B-frags via cvt_pk + permlane32_swap (P never leaves regs)
        u32x4 pbw0, pbw1;
        {
            unsigned int a0, a1, c0, c1;
            asm("v_cvt_pk_bf16_f32 %0, %1, %2" : "=v"(a0) : "v"(s[0]), "v"(s[1]));
            asm("v_cvt_pk_bf16_f32 %0, %1, %2" : "=v"(a1) : "v"(s[2]), "v"(s[3]));
            asm("v_cvt_pk_bf16_f32 %0, %1, %2" : "=v"(c0) : "v"(s[4]), "v"(s[5]));
            asm("v_cvt_pk_bf16_f32 %0, %1, %2" : "=v"(c1) : "v"(s[6]), "v"(s[7]));
            asm volatile("v_permlane32_swap_b32 %0, %1" : "+v"(a0), "+v"(c0));
            asm volatile("v_permlane32_swap_b32 %0, %1" : "+v"(a1), "+v"(c1));
            pbw0 = (u32x4){a0, a1, c0, c1};
        }
        {
            unsigned int a0, a1, c0, c1;
            asm("v_cvt_pk_bf16_f32 %0, %1, %2" : "=v"(a0) : "v"(s[8]),  "v"(s[9]));
            asm("v_cvt_pk_bf16_f32 %0, %1, %2" : "=v"(a1) : "v"(s[10]), "v"(s[11]));
            asm("v_cvt_pk_bf16_f32 %0, %1, %2" : "=v"(c0) : "v"(s[12]), "v"(s[13]));
            asm("v_cvt_pk_bf16_f32 %0, %1, %2" : "=v"(c1) : "v"(s[14]), "v"(s[15]));
            asm volatile("v_permlane32_swap_b32 %0, %1" : "+v"(a0), "+v"(c0));
            asm volatile("v_permlane32_swap_b32 %0, %1" : "+v"(a1), "+v"(c1));
            pbw1 = (u32x4){a0, a1, c0, c1};
        }

        // O^T += V * P^T, V A-frags straight from L2 (tiled layout, 16B contiguous)
        const bf16* vp = v + ((size_t)(mq * 18 + i) * 128 + col) * 32 + hi * 8;
        __builtin_amdgcn_s_setprio(1);
        {
            bf16x8 pf = __builtin_bit_cast(bf16x8, pbw0);
            o0 = __builtin_amdgcn_mfma_f32_32x32x16_bf16(*(const bf16x8*)(vp + 0*1024), pf, o0, 0, 0, 0);
            o1 = __builtin_amdgcn_mfma_f32_32x32x16_bf16(*(const bf16x8*)(vp + 1*1024), pf, o1, 0, 0, 0);
            o2 = __builtin_amdgcn_mfma_f32_32x32x16_bf16(*(const bf16x8*)(vp + 2*1024), pf, o2, 0, 0, 0);
            o3 = __builtin_amdgcn_mfma_f32_32x32x16_bf16(*(const bf16x8*)(vp + 3*1024), pf, o3, 0, 0, 0);
        }
        {
            bf16x8 pf = __builtin_bit_cast(bf16x8, pbw1);
            o0 = __builtin_amdgcn_mfma_f32_32x32x16_bf16(*(const bf16x8*)(vp + 0*1024 + 16), pf, o0, 0, 0, 0);
            o1 = __builtin_amdgcn_mfma_f32_32x32x16_bf16(*(const bf16x8*)(vp + 1*1024 + 16), pf, o1, 0, 0, 0);
            o2 = __builtin_amdgcn_mfma_f32_32x32x16_bf16(*(const bf16x8*)(vp + 2*1024 + 16), pf, o2, 0, 0, 0);
            o3 = __builtin_amdgcn_mfma_f32_32x32x16_bf16(*(const bf16x8*)(vp + 3*1024 + 16), pf, o3, 0, 0, 0);
        }
        __builtin_amdgcn_s_setprio(0);
    }

    // 4-way reduction across mq via LDS tree (epilogue only; all static indices).
    float* buf0 = RED;            // 16 KB
    float* buf1 = RED + 4096;     // 16 KB

    auto wpart = [&](float* buf, const f32x16& a, int cb) {
        #pragma unroll
        for (int g = 0; g < 4; ++g) {
            f32x4 v4;
            #pragma unroll
            for (int j = 0; j < 4; ++j) v4[j] = a[g * 4 + j];
            *(f32x4*)&buf[lane * 64 + (((cb * 4 + g) ^ (lane & 15)) * 4)] = v4;
        }
    };
    auto rpart = [&](float* buf, f32x16& a, int cb) {
        #pragma unroll
        for (int g = 0; g < 4; ++g) {
            f32x4 v4 = *(const f32x4*)&buf[lane * 64 + (((cb * 4 + g) ^ (lane & 15)) * 4)];
            #pragma unroll
            for (int j = 0; j < 4; ++j) a[g * 4 + j] += v4[j];
        }
    };

    __syncthreads();
    if (mq == 2) { wpart(buf0, o0, 0); wpart(buf0, o1, 1); wpart(buf0, o2, 2); wpart(buf0, o3, 3); }
    if (mq == 3) { wpart(buf1, o0, 0); wpart(buf1, o1, 1); wpart(buf1, o2, 2); wpart(buf1, o3, 3); }
    __syncthreads();
    if (mq == 0) { rpart(buf0, o0, 0); rpart(buf0, o1, 1); rpart(buf0, o2, 2); rpart(buf0, o3, 3); }
    if (mq == 1) { rpart(buf1, o0, 0); rpart(buf1, o1, 1); rpart(buf1, o2, 2); rpart(buf1, o3, 3); }
    __syncthreads();
    if (mq == 1) { wpart(buf0, o0, 0); wpart(buf0, o1, 1); wpart(buf0, o2, 2); wpart(buf0, o3, 3); }
    __syncthreads();
    if (mq == 0) {
        rpart(buf0, o0, 0); rpart(buf0, o1, 1); rpart(buf0, o2, 2); rpart(buf0, o3, 3);
        #pragma unroll
        for (int r = 0; r < 16; ++r) {
            int cr = (r & 3) + 8 * (r >> 2) + 4 * hi;
            outy[(size_t)(0 * 32 + cr) * NHW + nw + col] = o0[r];
            outy[(size_t)(1 * 32 + cr) * NHW + nw + col] = o1[r];
            outy[(size_t)(2 * 32 + cr) * NHW + nw + col] = o2[r];
            outy[(size_t)(3 * 32 + cr) * NHW + nw + col] = o3[r];
        }
    }
}

extern "C" void kernel_launch(void* const* d_in, const int* in_sizes, int n_in,
                              void* d_out, int out_size, void* d_ws, size_t ws_size,
                              hipStream_t stream) {
    const float* x1  = (const float*)d_in[0];
    const float* x2  = (const float*)d_in[1];
    const float* wv1 = (const float*)d_in[2];  const float* bv1 = (const float*)d_in[3];
    const float* wk1 = (const float*)d_in[4];  const float* bk1 = (const float*)d_in[5];
    const float* wq1 = (const float*)d_in[6];  const float* bq1 = (const float*)d_in[7];
    const float* wv2 = (const float*)d_in[8];  const float* bv2 = (const float*)d_in[9];
    const float* wk2 = (const float*)d_in[10]; const float* bk2 = (const float*)d_in[11];
    const float* wq2 = (const float*)d_in[12]; const float* bq2 = (const float*)d_in[13];
    float* out = (float*)d_out;

    // ws layout (bf16): Qt[2][B][2304][128] | Kt | Vt[2][B][72][128][32] | wb[6][128*256]
    size_t per = (size_t)2 * NB * NHW * NCI;
    bf16* Qt = (bf16*)d_ws;
    bf16* Kt = Qt + per;
    bf16* Vt = Kt + per;
    bf16* wb = Vt + per;

    wconv_kernel<<<dim3(96), dim3(256), 0, stream>>>(wv1, wk1, wq1, wv2, wk2, wq2, wb);

    qkv_kernel<<<dim3(NB * 2 * NT32), dim3(256), 0, stream>>>(
        x1, x2, wb, bv1, bk1, bq1, bv2, bk2, bq2, Qt, Kt, Vt, out);

    attn_kernel<<<dim3(NB * 2 * NT32), dim3(256), 0, stream>>>(Qt, Kt, Vt, out);
}

// Round 6
// 284.454 us; speedup vs baseline: 1.0156x; 1.0156x over previous
//
#include <hip/hip_runtime.h>
#include <hip/hip_bf16.h>

// SCM_39676907888322: sigmoid-gated cross attention. fp32 I/O, bf16 MFMA compute.
// R10: R9 (barrier-free, direct-from-L2, tiled Vt) + software pipelining.
// R9's failure was dependent-load latency (MfmaUtil 11.5%, zero conflicts,
// zero spill): load->wait->MFMA chains with ~2 waves/SIMD. Fix:
//  - K-frags cross-iter register double-buffered (kfA/kfB, unroll-2, static
//    names per rule 20): tile i+1's K loads issue at top of tile i.
//  - V-frags issued at iter start, consumed after QK+sigmoid (~250 cyc cover).
//  - __launch_bounds__(256,2): 256-reg cap (peak live ~220 incl 64 AGPR acc).
// qkv/wconv/layouts/reduction identical to R9 (all verified).

typedef __bf16 bf16;
typedef __bf16 bf16x8 __attribute__((ext_vector_type(8)));
typedef __bf16 bf16x4 __attribute__((ext_vector_type(4)));
typedef float f32x4 __attribute__((ext_vector_type(4)));
typedef float f32x16 __attribute__((ext_vector_type(16)));
typedef unsigned int u32x4 __attribute__((ext_vector_type(4)));

#define NB 8
#define NC 256
#define NCI 128
#define NHW 2304
#define NT32 72    // 2304 / 32  (qkv n-tiles)

__global__ __launch_bounds__(256) void wconv_kernel(
    const float* __restrict__ w0, const float* __restrict__ w1,
    const float* __restrict__ w2, const float* __restrict__ w3,
    const float* __restrict__ w4, const float* __restrict__ w5,
    bf16* __restrict__ dst)
{
    int idx = (blockIdx.x * 256 + threadIdx.x) * 8;   // 6*32768 total
    int m = idx >> 15;                                 // matrix id (block-uniform)
    int off = idx & 32767;
    const float* w = (m == 0) ? w0 : (m == 1) ? w1 : (m == 2) ? w2
                   : (m == 3) ? w3 : (m == 4) ? w4 : w5;
    f32x4 a0 = *(const f32x4*)(w + off);
    f32x4 a1 = *(const f32x4*)(w + off + 4);
    bf16x8 o;
    #pragma unroll
    for (int j = 0; j < 4; ++j) { o[j] = (bf16)a0[j]; o[4 + j] = (bf16)a1[j]; }
    *(bf16x8*)(dst + idx) = o;
}

__global__ __launch_bounds__(256) void qkv_kernel(
    const float* __restrict__ x1, const float* __restrict__ x2,
    const bf16* __restrict__ wb,
    const float* __restrict__ bv1, const float* __restrict__ bk1, const float* __restrict__ bq1,
    const float* __restrict__ bv2, const float* __restrict__ bk2, const float* __restrict__ bq2,
    bf16* __restrict__ Qt, bf16* __restrict__ Kt, bf16* __restrict__ Vt,
    float* __restrict__ out)
{
    // Xt[n][c] bf16, 32 rows, padded stride 264
    __shared__ __align__(16) bf16 Xt[32 * 264];

    int gid = blockIdx.x;
    int nt = gid % NT32;
    int s = (gid / NT32) & 1;
    int b = gid / (2 * NT32);
    int n0 = nt * 32;

    const float* x = s ? x2 : x1;
    // wb layout: [v1,k1,q1,v2,k2,q2] each 128*256
    const bf16* wv = wb + (size_t)(s * 3 + 0) * (NCI * NC);
    const bf16* wk = wb + (size_t)(s * 3 + 1) * (NCI * NC);
    const bf16* wq = wb + (size_t)(s * 3 + 2) * (NCI * NC);
    const float* bv = s ? bv2 : bv1;
    const float* bk = s ? bk2 : bk1;
    const float* bq = s ? bq2 : bq1;
    float* outy = out + (size_t)s * (NB * 384 * NHW);

    int tid = threadIdx.x;
    // Stage X tile (256 c x 32 n) into LDS transposed (bf16); fp32 concat passthrough.
    {
        int n_off = (tid & 3) * 8;       // 0,8,16,24
        int c0l = tid >> 2;              // 0..63
        #pragma unroll
        for (int i = 0; i < 4; ++i) {
            int c = c0l + i * 64;
            const float* src = x + ((size_t)(b * NC + c) * NHW + n0 + n_off);
            f32x4 a0 = *(const f32x4*)src;
            f32x4 a1 = *(const f32x4*)(src + 4);
            float* dsty = outy + ((size_t)(b * 384 + c) * NHW + n0 + n_off);
            *(f32x4*)dsty = a0;
            *(f32x4*)(dsty + 4) = a1;
            #pragma unroll
            for (int j = 0; j < 4; ++j) {
                Xt[(n_off + j) * 264 + c] = (bf16)a0[j];
                Xt[(n_off + 4 + j) * 264 + c] = (bf16)a1[j];
            }
        }
    }
    __syncthreads();

    int lane = tid & 63;
    int wid = tid >> 6;                  // wave 0..3 -> ci strip of 32
    int row = lane & 15, quad = lane >> 4;
    int ci_base = wid * 32;

    f32x4 acc[3][2][2];                  // [q,k,v][mi][j]
    #pragma unroll
    for (int t = 0; t < 3; ++t)
        #pragma unroll
        for (int mi = 0; mi < 2; ++mi)
            #pragma unroll
            for (int j = 0; j < 2; ++j)
                acc[t][mi][j] = (f32x4){0.f, 0.f, 0.f, 0.f};

    const bf16* wptr[3] = {wq, wk, wv};
    #pragma unroll
    for (int ks = 0; ks < 8; ++ks) {
        int c0 = ks * 32 + quad * 8;
        bf16x8 bfrag[2];
        #pragma unroll
        for (int j = 0; j < 2; ++j)
            bfrag[j] = *(const bf16x8*)&Xt[(j * 16 + row) * 264 + c0];
        #pragma unroll
        for (int t = 0; t < 3; ++t) {
            #pragma unroll
            for (int mi = 0; mi < 2; ++mi) {
                bf16x8 afrag = *(const bf16x8*)&wptr[t][(size_t)(ci_base + mi * 16 + row) * NC + c0];
                #pragma unroll
                for (int j = 0; j < 2; ++j)
                    acc[t][mi][j] = __builtin_amdgcn_mfma_f32_16x16x32_bf16(
                        afrag, bfrag[j], acc[t][mi][j], 0, 0, 0);
            }
        }
    }

    // Epilogue: +bias (fp32), write Qt/Kt (n,128) bf16 8B stores.
    // V goes to the TILED layout Vt[(s,b)][mt(72)][c(128)][mm(32)] so attn's
    // PV A-frags are 16B-contiguous (this block covers exactly tile mt = nt).
    size_t qkbase = ((size_t)s * NB + b) * NHW * NCI;
    size_t vbase  = ((size_t)s * NB + b) * NCI * NHW;
    #pragma unroll
    for (int mi = 0; mi < 2; ++mi) {
        int ci0 = ci_base + mi * 16 + quad * 4;
        f32x4 bq4 = *(const f32x4*)&bq[ci0];
        f32x4 bk4 = *(const f32x4*)&bk[ci0];
        f32x4 bv4 = *(const f32x4*)&bv[ci0];
        #pragma unroll
        for (int j = 0; j < 2; ++j) {
            int n = n0 + j * 16 + row;   // D col = lane&15
            bf16x4 pk;
            #pragma unroll
            for (int r = 0; r < 4; ++r) pk[r] = (bf16)(acc[0][mi][j][r] + bq4[r]);
            *(bf16x4*)&Qt[qkbase + (size_t)n * NCI + ci0] = pk;
            #pragma unroll
            for (int r = 0; r < 4; ++r) pk[r] = (bf16)(acc[1][mi][j][r] + bk4[r]);
            *(bf16x4*)&Kt[qkbase + (size_t)n * NCI + ci0] = pk;
            #pragma unroll
            for (int r = 0; r < 4; ++r)
                Vt[vbase + (size_t)(nt * 128 + ci0 + r) * 32 + (j * 16 + row)] =
                    (bf16)(acc[2][mi][j][r] + bv4[r]);
        }
    }
}

__global__ __launch_bounds__(256, 2) void attn_kernel(
    const bf16* __restrict__ Qt, const bf16* __restrict__ Kt, const bf16* __restrict__ Vt,
    float* __restrict__ out)
{
    __shared__ __align__(16) float RED[8192];   // 32 KB, epilogue reduction only

    int gid = blockIdx.x;                // 1152 = 8 b x 2 dir x 72 nt
    int b = gid & 7;                     // XCD pin: all blocks of batch b -> XCD b
    int dir = (gid >> 3) & 1;
    int nt = gid >> 4;                   // 0..71

    int tid = threadIdx.x;
    int lane = tid & 63;
    int mq = tid >> 6;                   // wave -> m-quarter (576 m rows, 18 tiles)
    int col = lane & 31, hi = lane >> 5;

    int sq = dir, skv = dir ^ 1;
    const bf16* q = Qt + ((size_t)sq  * NB + b) * (NHW * NCI);
    const bf16* k = Kt + ((size_t)skv * NB + b) * (NHW * NCI);
    const bf16* v = Vt + ((size_t)skv * NB + b) * (NCI * NHW);   // tiled [mt][c][32]
    float* outy = out + (size_t)dir * (NB * 384 * NHW) + ((size_t)b * 384 + 256) * NHW;

    int nw = nt * 32;                    // block's 32 Q rows (shared by all 4 waves)

    bf16x8 qf[8];                        // Q B-frags, resident
    #pragma unroll
    for (int j = 0; j < 8; ++j)
        qf[j] = *(const bf16x8*)&q[(size_t)(nw + col) * NCI + j * 16 + hi * 8];

    f32x16 o0, o1, o2, o3;               // O^T partial acc (this wave's m-quarter)
    #pragma unroll
    for (int j = 0; j < 16; ++j) { o0[j] = 0.f; o1[j] = 0.f; o2[j] = 0.f; o3[j] = 0.f; }

    // Software pipeline: K-frags double-buffered across iterations.
    const bf16* kbase = k + (size_t)(mq * 576 + col) * NCI + hi * 8;
    const bf16* vbase = v + ((size_t)(mq * 18) * 128 + col) * 32 + hi * 8;

    bf16x8 kfA[8], kfB[8];
    #pragma unroll
    for (int j = 0; j < 8; ++j) kfA[j] = *(const bf16x8*)(kbase + j * 16);

    auto body = [&](bf16x8 (&cur)[8], bf16x8 (&nxt)[8], int i) {
        // V-frags for tile i: issue FIRST (independent; ~QK+sigmoid of cover)
        const bf16* vp = vbase + (size_t)i * 4096;       // 128*32 bf16 per tile
        bf16x8 vf[8];
        #pragma unroll
        for (int ct = 0; ct < 4; ++ct) {
            vf[2 * ct]     = *(const bf16x8*)(vp + ct * 1024);
            vf[2 * ct + 1] = *(const bf16x8*)(vp + ct * 1024 + 16);
        }
        // K prefetch for tile i+1 (consumed next call; full iter of cover)
        int inx = (i + 1 < 18) ? (i + 1) : 0;
        const bf16* kpn = kbase + (size_t)inx * 32 * NCI;
        #pragma unroll
        for (int j = 0; j < 8; ++j) nxt[j] = *(const bf16x8*)(kpn + j * 16);

        // S^T = K * Q^T : 32 m x 32 n (swapped operands)
        f32x16 s;
        #pragma unroll
        for (int j = 0; j < 16; ++j) s[j] = 0.f;
        __builtin_amdgcn_s_setprio(1);
        #pragma unroll
        for (int j = 0; j < 8; ++j)
            s = __builtin_amdgcn_mfma_f32_32x32x16_bf16(cur[j], qf[j], s, 0, 0, 0);
        __builtin_amdgcn_s_setprio(0);

        // sigmoid in place (S^T reg r = S^T[m=(r&3)+8*(r>>2)+4*hi][n=col])
        #pragma unroll
        for (int r = 0; r < 16; ++r) {
            float e = __expf(-s[r]);
            s[r] = __builtin_amdgcn_rcpf(1.0f + e);
        }
        // P^T bf16 B-frags via cvt_pk + permlane32_swap (P never leaves regs)
        u32x4 pbw0, pbw1;
        {
            unsigned int a0, a1, c0, c1;
            asm("v_cvt_pk_bf16_f32 %0, %1, %2" : "=v"(a0) : "v"(s[0]), "v"(s[1]));
            asm("v_cvt_pk_bf16_f32 %0, %1, %2" : "=v"(a1) : "v"(s[2]), "v"(s[3]));
            asm("v_cvt_pk_bf16_f32 %0, %1, %2" : "=v"(c0) : "v"(s[4]), "v"(s[5]));
            asm("v_cvt_pk_bf16_f32 %0, %1, %2" : "=v"(c1) : "v"(s[6]), "v"(s[7]));
            asm volatile("v_permlane32_swap_b32 %0, %1" : "+v"(a0), "+v"(c0));
            asm volatile("v_permlane32_swap_b32 %0, %1" : "+v"(a1), "+v"(c1));
            pbw0 = (u32x4){a0, a1, c0, c1};
        }
        {
            unsigned int a0, a1, c0, c1;
            asm("v_cvt_pk_bf16_f32 %0, %1, %2" : "=v"(a0) : "v"(s[8]),  "v"(s[9]));
            asm("v_cvt_pk_bf16_f32 %0, %1, %2" : "=v"(a1) : "v"(s[10]), "v"(s[11]));
            asm("v_cvt_pk_bf16_f32 %0, %1, %2" : "=v"(c0) : "v"(s[12]), "v"(s[13]));
            asm("v_cvt_pk_bf16_f32 %0, %1, %2" : "=v"(c1) : "v"(s[14]), "v"(s[15]));
            asm volatile("v_permlane32_swap_b32 %0, %1" : "+v"(a0), "+v"(c0));
            asm volatile("v_permlane32_swap_b32 %0, %1" : "+v"(a1), "+v"(c1));
            pbw1 = (u32x4){a0, a1, c0, c1};
        }

        // O^T += V * P^T
        __builtin_amdgcn_s_setprio(1);
        {
            bf16x8 pf = __builtin_bit_cast(bf16x8, pbw0);
            o0 = __builtin_amdgcn_mfma_f32_32x32x16_bf16(vf[0], pf, o0, 0, 0, 0);
            o1 = __builtin_amdgcn_mfma_f32_32x32x16_bf16(vf[2], pf, o1, 0, 0, 0);
            o2 = __builtin_amdgcn_mfma_f32_32x32x16_bf16(vf[4], pf, o2, 0, 0, 0);
            o3 = __builtin_amdgcn_mfma_f32_32x32x16_bf16(vf[6], pf, o3, 0, 0, 0);
        }
        {
            bf16x8 pf = __builtin_bit_cast(bf16x8, pbw1);
            o0 = __builtin_amdgcn_mfma_f32_32x32x16_bf16(vf[1], pf, o0, 0, 0, 0);
            o1 = __builtin_amdgcn_mfma_f32_32x32x16_bf16(vf[3], pf, o1, 0, 0, 0);
            o2 = __builtin_amdgcn_mfma_f32_32x32x16_bf16(vf[5], pf, o2, 0, 0, 0);
            o3 = __builtin_amdgcn_mfma_f32_32x32x16_bf16(vf[7], pf, o3, 0, 0, 0);
        }
        __builtin_amdgcn_s_setprio(0);
    };

    #pragma unroll 1
    for (int ii = 0; ii < 9; ++ii) {     // 18 tiles, unroll-2 with static A/B roles
        body(kfA, kfB, 2 * ii);
        body(kfB, kfA, 2 * ii + 1);
    }

    // 4-way reduction across mq via LDS tree (epilogue only; all static indices).
    float* buf0 = RED;            // 16 KB
    float* buf1 = RED + 4096;     // 16 KB

    auto wpart = [&](float* buf, const f32x16& a, int cb) {
        #pragma unroll
        for (int g = 0; g < 4; ++g) {
            f32x4 v4;
            #pragma unroll
            for (int j = 0; j < 4; ++j) v4[j] = a[g * 4 + j];
            *(f32x4*)&buf[lane * 64 + (((cb * 4 + g) ^ (lane & 15)) * 4)] = v4;
        }
    };
    auto rpart = [&](float* buf, f32x16& a, int cb) {
        #pragma unroll
        for (int g = 0; g < 4; ++g) {
            f32x4 v4 = *(const f32x4*)&buf[lane * 64 + (((cb * 4 + g) ^ (lane & 15)) * 4)];
            #pragma unroll
            for (int j = 0; j < 4; ++j) a[g * 4 + j] += v4[j];
        }
    };

    __syncthreads();
    if (mq == 2) { wpart(buf0, o0, 0); wpart(buf0, o1, 1); wpart(buf0, o2, 2); wpart(buf0, o3, 3); }
    if (mq == 3) { wpart(buf1, o0, 0); wpart(buf1, o1, 1); wpart(buf1, o2, 2); wpart(buf1, o3, 3); }
    __syncthreads();
    if (mq == 0) { rpart(buf0, o0, 0); rpart(buf0, o1, 1); rpart(buf0, o2, 2); rpart(buf0, o3, 3); }
    if (mq == 1) { rpart(buf1, o0, 0); rpart(buf1, o1, 1); rpart(buf1, o2, 2); rpart(buf1, o3, 3); }
    __syncthreads();
    if (mq == 1) { wpart(buf0, o0, 0); wpart(buf0, o1, 1); wpart(buf0, o2, 2); wpart(buf0, o3, 3); }
    __syncthreads();
    if (mq == 0) {
        rpart(buf0, o0, 0); rpart(buf0, o1, 1); rpart(buf0, o2, 2); rpart(buf0, o3, 3);
        #pragma unroll
        for (int r = 0; r < 16; ++r) {
            int cr = (r & 3) + 8 * (r >> 2) + 4 * hi;
            outy[(size_t)(0 * 32 + cr) * NHW + nw + col] = o0[r];
            outy[(size_t)(1 * 32 + cr) * NHW + nw + col] = o1[r];
            outy[(size_t)(2 * 32 + cr) * NHW + nw + col] = o2[r];
            outy[(size_t)(3 * 32 + cr) * NHW + nw + col] = o3[r];
        }
    }
}

extern "C" void kernel_launch(void* const* d_in, const int* in_sizes, int n_in,
                              void* d_out, int out_size, void* d_ws, size_t ws_size,
                              hipStream_t stream) {
    const float* x1  = (const float*)d_in[0];
    const float* x2  = (const float*)d_in[1];
    const float* wv1 = (const float*)d_in[2];  const float* bv1 = (const float*)d_in[3];
    const float* wk1 = (const float*)d_in[4];  const float* bk1 = (const float*)d_in[5];
    const float* wq1 = (const float*)d_in[6];  const float* bq1 = (const float*)d_in[7];
    const float* wv2 = (const float*)d_in[8];  const float* bv2 = (const float*)d_in[9];
    const float* wk2 = (const float*)d_in[10]; const float* bk2 = (const float*)d_in[11];
    const float* wq2 = (const float*)d_in[12]; const float* bq2 = (const float*)d_in[13];
    float* out = (float*)d_out;

    // ws layout (bf16): Qt[2][B][2304][128] | Kt | Vt[2][B][72][128][32] | wb[6][128*256]
    size_t per = (size_t)2 * NB * NHW * NCI;
    bf16* Qt = (bf16*)d_ws;
    bf16* Kt = Qt + per;
    bf16* Vt = Kt + per;
    bf16* wb = Vt + per;

    wconv_kernel<<<dim3(96), dim3(256), 0, stream>>>(wv1, wk1, wq1, wv2, wk2, wq2, wb);

    qkv_kernel<<<dim3(NB * 2 * NT32), dim3(256), 0, stream>>>(
        x1, x2, wb, bv1, bk1, bq1, bv2, bk2, bq2, Qt, Kt, Vt, out);

    attn_kernel<<<dim3(NB * 2 * NT32), dim3(256), 0, stream>>>(Qt, Kt, Vt, out);
}